// Round 12
// baseline (786.860 us; speedup 1.0000x reference)
//
#include <hip/hip_runtime.h>
#include <math.h>

#define N_ 2048
#define NF_IN 64
#define D_ 256
#define H_ 8
#define HD_ 32
#define L_ 6
#define FFN_ 1024
#define E_ 32768
#define EF_ 16
#define NF 2049      // N+1 tokens (CLS at row 0)
#define MAXDEG_ 64
#define BSTRIDE 2112 // padded row stride: bytes for fp8 bias, shorts for Vt
#define RPAD 2112    // padded row count for attention partials
#define NSPLIT 4     // key splits for flash attention
#define LOG2E 1.4426950408889634f

typedef __attribute__((ext_vector_type(8))) short bf16x8;
typedef __attribute__((ext_vector_type(4))) float f32x4;

__device__ inline unsigned short f2b(float f){
  union { float f; unsigned u; } v; v.f = f;
  unsigned r = (v.u + 0x7fffu + ((v.u >> 16) & 1u)) >> 16;
  return (unsigned short)r;
}
__device__ inline float b2f(short s){
  union { unsigned u; float f; } v; v.u = ((unsigned)(unsigned short)s) << 16;
  return v.f;
}

// manual OCP e4m3fn encode, RNE (prep-path only)
__device__ inline unsigned char f2fp8(float f){
  unsigned u = __float_as_uint(f);
  unsigned s = (u >> 24) & 0x80u;
  float a = fabsf(f);
  if (a >= 448.f) return (unsigned char)(s | 0x7Eu);
  if (a < 0.015625f){                      // denormal region (incl. 0)
    int k = (int)rintf(a * 512.f);         // step 2^-9; k=8 rolls into 2^-6
    return (unsigned char)(s | (unsigned)k);
  }
  int e; float m = frexpf(a, &e);          // a = m*2^e, m in [0.5,1)
  int E = e - 1;
  int m3 = (int)rintf(m * 16.f) - 8;       // 0..8
  if (m3 == 8){ E++; m3 = 0; }
  if (E > 8){ E = 8; m3 = 6; }
  if (E == 8 && m3 > 6) m3 = 6;
  return (unsigned char)(s | (unsigned)((E + 7) << 3) | (unsigned)m3);
}
__device__ inline float fp82f(unsigned char b){
  return __builtin_amdgcn_cvt_f32_fp8((int)b, 0);
}

__device__ inline void atomic_add_fp8(unsigned char* p, float add){
  unsigned* wp = (unsigned*)((size_t)p & ~(size_t)3);
  int sh = (int)((size_t)p & 3) * 8;
  unsigned old = *wp, assumed;
  do {
    assumed = old;
    unsigned char cur = (unsigned char)((assumed >> sh) & 0xFFu);
    float f = fp82f(cur) + add;
    unsigned nw = (assumed & ~(0xFFu << sh)) | ((unsigned)f2fp8(f) << sh);
    old = atomicCAS(wp, assumed, nw);
  } while (old != assumed);
}

__device__ inline float wred_sum(float v){
  #pragma unroll
  for (int o = 32; o > 0; o >>= 1) v += __shfl_down(v, o, 64);
  return v;
}

__global__ void zero_int(int* p, int n){
  int i = blockIdx.x * blockDim.x + threadIdx.x;
  if (i < n) p[i] = 0;
}

__global__ void deg_count(const int* __restrict__ ei, int* __restrict__ ind,
                          int* __restrict__ outd){
  int e = blockIdx.x * blockDim.x + threadIdx.x;
  if (e >= E_) return;
  atomicAdd(&outd[ei[e]], 1);
  atomicAdd(&ind[ei[E_ + e]], 1);
}

__global__ void embed_k(const float* __restrict__ x, const float* __restrict__ W,
                        const float* __restrict__ b, const float* __restrict__ inE,
                        const float* __restrict__ outE, const int* __restrict__ ind,
                        const int* __restrict__ outd, const float* __restrict__ cls,
                        float* __restrict__ h){
  int i = blockIdx.x, d = threadIdx.x;
  if (i == 0){ h[d] = cls[d]; return; }
  int n = i - 1;
  const float4* xr = (const float4*)(x + (long)n * NF_IN);
  const float4* wr = (const float4*)(W + (long)d * NF_IN);
  float acc = b[d];
  #pragma unroll
  for (int k = 0; k < NF_IN / 4; k++){
    float4 a = xr[k], w = wr[k];
    acc += a.x * w.x + a.y * w.y + a.z * w.z + a.w * w.w;
  }
  int id = min(ind[n], MAXDEG_), od = min(outd[n], MAXDEG_);
  acc += inE[(long)id * D_ + d] + outE[(long)od * D_ + d];
  h[(long)i * D_ + d] = acc;
}

// bias stored as fp8 of (bias * log2e) — exp2-domain; grid NF
__global__ void bias_fill(const int* __restrict__ dist, const float* __restrict__ db,
                          unsigned char* __restrict__ bb){
  __shared__ unsigned char lut8[10][H_];
  int i = blockIdx.x;
  if (threadIdx.x < 80)
    ((unsigned char*)lut8)[threadIdx.x] = f2fp8(db[threadIdx.x] * LOG2E);
  __syncthreads();
  for (int u = threadIdx.x; u < BSTRIDE / 8; u += 256){
    int dp[8];
    #pragma unroll
    for (int k = 0; k < 8; k++){
      int j = u * 8 + k;
      int d = 0;
      if (i > 0 && j > 0 && j < NF){
        int dv = dist[(long)(i - 1) * N_ + (j - 1)];
        d = max(0, min(dv, 9));
      }
      dp[k] = (j < NF) ? d : -1;
    }
    #pragma unroll
    for (int h = 0; h < H_; h++){
      unsigned lo = 0, hi = 0;
      #pragma unroll
      for (int k = 0; k < 4; k++){
        unsigned b0 = (dp[k] >= 0) ? lut8[dp[k]][h] : 0u;
        unsigned b1 = (dp[4 + k] >= 0) ? lut8[dp[4 + k]][h] : 0u;
        lo |= b0 << (8 * k);
        hi |= b1 << (8 * k);
      }
      *(uint2*)(bb + ((long)h * NF + i) * BSTRIDE + u * 8) = make_uint2(lo, hi);
    }
  }
}

// sparse edge-feature bias: byte-CAS fp8 add (also log2e-scaled)
__global__ void edge_bias(const float* __restrict__ ea, const float* __restrict__ W,
                          const float* __restrict__ b, const int* __restrict__ ei,
                          unsigned char* __restrict__ bb){
  int e = blockIdx.x * blockDim.x + threadIdx.x;
  if (e >= E_) return;
  float a[EF_];
  #pragma unroll
  for (int k = 0; k < EF_; k++) a[k] = ea[(long)e * EF_ + k];
  int src = ei[e], dst = ei[E_ + e];
  #pragma unroll
  for (int h = 0; h < H_; h++){
    float p = b[h];
    #pragma unroll
    for (int k = 0; k < EF_; k++) p += a[k] * W[h * EF_ + k];
    atomic_add_fp8(bb + ((long)h * NF + src + 1) * BSTRIDE + (dst + 1), p * LOG2E);
  }
}

// all weight conversions in one dispatch
__global__ void w2b_all(const float* __restrict__ qw, const float* __restrict__ kw,
                        const float* __restrict__ vw, const float* __restrict__ ow,
                        const float* __restrict__ f1w, const float* __restrict__ f2w,
                        short* __restrict__ wqkv, short* __restrict__ owb,
                        short* __restrict__ f1wb, short* __restrict__ f2wb){
  long i = (long)blockIdx.x * 256 + threadIdx.x;
  const long DD = (long)D_ * D_, LDD = (long)L_ * DD, LFD = (long)L_ * FFN_ * D_;
  if (i < LDD){
    long l = i / DD, r = i - l * DD;
    wqkv[l * 3 * DD + r]          = (short)f2b(qw[i]);
    wqkv[l * 3 * DD + DD + r]     = (short)f2b(kw[i]);
    wqkv[l * 3 * DD + 2 * DD + r] = (short)f2b(vw[i]);
    owb[i] = (short)f2b(ow[i]);
  }
  if (i < LFD){
    f1wb[i] = (short)f2b(f1w[i]);
    f2wb[i] = (short)f2b(f2w[i]);
  }
}

__global__ void ln_k(const float* __restrict__ in, const float* __restrict__ s,
                     const float* __restrict__ b, float* __restrict__ outf,
                     short* __restrict__ outb, int dup0){
  __shared__ float r1[4], r2[4];
  int i = blockIdx.x, d = threadIdx.x;
  float v = in[(long)i * D_ + d];
  float s1 = wred_sum(v), s2 = wred_sum(v * v);
  if ((d & 63) == 0){ r1[d >> 6] = s1; r2[d >> 6] = s2; }
  __syncthreads();
  float S1 = r1[0] + r1[1] + r1[2] + r1[3];
  float S2 = r2[0] + r2[1] + r2[2] + r2[3];
  float m = S1 * (1.0f / D_);
  float var = S2 * (1.0f / D_) - m * m;
  float y = (v - m) * rsqrtf(var + 1e-5f) * s[d] + b[d];
  if (outf){
    outf[(long)i * D_ + d] = y;
    if (dup0 && i == 0) outf[(long)NF * D_ + d] = y;
  }
  if (outb) outb[(long)i * D_ + d] = (short)f2b(y);
}

// ---- fused QKV MFMA GEMM: grid (33, 4, 3). z==0 (Q) is pre-scaled by
// (1/sqrt(HD))*log2e so fattn's softmax works in the exp2 domain.
// z==2 (V): epilogue transposes the 64x64 tile through LDS so Vtg rows are
// written with coalesced 128B segments.
__global__ __launch_bounds__(256) void qkv_gemm(const short* __restrict__ A,
    const short* __restrict__ Wall, const float* __restrict__ qb,
    const float* __restrict__ kb, const float* __restrict__ vb,
    short* __restrict__ QKb, short* __restrict__ Vtg, int l){
  const int z = blockIdx.z;
  const short* W = Wall + ((long)(l * 3 + z)) * D_ * D_;
  const float* bsp = (z == 0) ? qb : (z == 1) ? kb : vb;
  __shared__ __align__(16) short As[64][40], Ws[64][40];
  __shared__ __align__(16) short Tt[64][72];   // V transpose buffer [dim][key]
  const int tid = threadIdx.x, lane = tid & 63, wave = tid >> 6;
  const int col = lane & 15, quad = lane >> 4;
  const int wm = wave & 1, wn = wave >> 1;
  const int bm = blockIdx.x * 64, bn = blockIdx.y * 64;
  const f32x4 zero4 = {0.f, 0.f, 0.f, 0.f};
  f32x4 acc[2][2] = {{zero4, zero4}, {zero4, zero4}};
  const int row = tid >> 2, seg = tid & 3;
  for (int k0 = 0; k0 < D_; k0 += 32){
    __syncthreads();
    bf16x8 av = (bf16x8)(short)0;
    int gm = bm + row;
    if (gm < NF) av = *(const bf16x8*)(A + (long)gm * D_ + k0 + seg * 8);
    *(bf16x8*)&As[row][seg * 8] = av;
    *(bf16x8*)&Ws[row][seg * 8] = *(const bf16x8*)(W + (long)(bn + row) * D_ + k0 + seg * 8);
    __syncthreads();
    bf16x8 a0 = *(const bf16x8*)&As[wm * 32 + col][quad * 8];
    bf16x8 a1 = *(const bf16x8*)&As[wm * 32 + 16 + col][quad * 8];
    bf16x8 b0 = *(const bf16x8*)&Ws[wn * 32 + col][quad * 8];
    bf16x8 b1 = *(const bf16x8*)&Ws[wn * 32 + 16 + col][quad * 8];
    acc[0][0] = __builtin_amdgcn_mfma_f32_16x16x32_bf16(a0, b0, acc[0][0], 0, 0, 0);
    acc[0][1] = __builtin_amdgcn_mfma_f32_16x16x32_bf16(a0, b1, acc[0][1], 0, 0, 0);
    acc[1][0] = __builtin_amdgcn_mfma_f32_16x16x32_bf16(a1, b0, acc[1][0], 0, 0, 0);
    acc[1][1] = __builtin_amdgcn_mfma_f32_16x16x32_bf16(a1, b1, acc[1][1], 0, 0, 0);
  }
  if (z < 2){
    const float qscale = 0.25501133194822025f;  // (1/sqrt(32)) * log2e
    #pragma unroll
    for (int i = 0; i < 2; i++)
      #pragma unroll
      for (int j = 0; j < 2; j++)
        #pragma unroll
        for (int r = 0; r < 4; r++){
          int gm = bm + wm * 32 + i * 16 + quad * 4 + r;
          if (gm >= NF) continue;
          int gn = bn + wn * 32 + j * 16 + col;
          float v = acc[i][j][r] + bsp[gn];
          if (z == 0) v *= qscale;
          QKb[(long)z * NF * D_ + (long)gm * D_ + gn] = (short)f2b(v);
        }
  } else {
    // transpose tile into LDS: Tt[dim][key]; rows gm>=NF hold finite values
    #pragma unroll
    for (int i = 0; i < 2; i++)
      #pragma unroll
      for (int j = 0; j < 2; j++){
        int ln_ = wn * 32 + j * 16 + col;     // local dim
        int lc = wm * 32 + i * 16 + quad * 4; // local key base (4 consecutive)
        float bsv = bsp[bn + ln_];
        short pk[4];
        #pragma unroll
        for (int r = 0; r < 4; r++) pk[r] = (short)f2b(acc[i][j][r] + bsv);
        *(short4*)&Tt[ln_][lc] = *(short4*)pk;
      }
    __syncthreads();
    int lr = tid >> 2, sg = tid & 3;
    bf16x8 v0 = *(const bf16x8*)&Tt[lr][sg * 16];
    bf16x8 v1 = *(const bf16x8*)&Tt[lr][sg * 16 + 8];
    short* dstp = Vtg + (long)(bn + lr) * BSTRIDE + bm + sg * 16;
    *(bf16x8*)dstp = v0;
    *(bf16x8*)(dstp + 8) = v1;
  }
}

// ---- generic MFMA GEMM.
// MERGE=1: A[gm][k] = (sum_q Opart[q][k/32][gm][k%32]) / (sum_q Lpart[q][k/32][gm])
// ATOM=1: atomicAdd partial into Cf (bias added by z==0 block); else bf16 out + ACT.
template<int ACT, int ATOM, int MERGE>
__global__ __launch_bounds__(256) void mgemm(const short* __restrict__ A,
    const float* __restrict__ Op, const float* __restrict__ Lp,
    const short* __restrict__ W, const float* __restrict__ bs,
    float* __restrict__ Cf, short* __restrict__ Cb,
    int M, int Nn, int Kc, int Kstride){
  __shared__ __align__(16) short As[64][40], Ws[64][40];
  const int tid = threadIdx.x, lane = tid & 63, wave = tid >> 6;
  const int col = lane & 15, quad = lane >> 4;
  const int wm = wave & 1, wn = wave >> 1;
  const int bm = blockIdx.x * 64, bn = blockIdx.y * 64;
  const int koff = blockIdx.z * Kc;
  const f32x4 zero4 = {0.f, 0.f, 0.f, 0.f};
  f32x4 acc[2][2] = {{zero4, zero4}, {zero4, zero4}};
  const int row = tid >> 2, seg = tid & 3;
  for (int k0 = 0; k0 < Kc; k0 += 32){
    __syncthreads();
    int gm = bm + row;
    if (MERGE){
      int kg = koff + k0 + seg * 8;
      int hh = kg >> 5, d0 = kg & 31;
      short sarr[8] = {0,0,0,0,0,0,0,0};
      if (gm < M){
        float o0=0,o1=0,o2=0,o3=0,o4=0,o5=0,o6=0,o7=0, sl=0.f;
        #pragma unroll
        for (int q = 0; q < NSPLIT; q++){
          long rb = (long)(q * H_ + hh) * RPAD + gm;
          const float* op = Op + rb * HD_ + d0;
          float4 v0 = *(const float4*)op, v1 = *(const float4*)(op + 4);
          o0 += v0.x; o1 += v0.y; o2 += v0.z; o3 += v0.w;
          o4 += v1.x; o5 += v1.y; o6 += v1.z; o7 += v1.w;
          sl += Lp[rb];
        }
        float inv = 1.0f / sl;
        sarr[0]=(short)f2b(o0*inv); sarr[1]=(short)f2b(o1*inv);
        sarr[2]=(short)f2b(o2*inv); sarr[3]=(short)f2b(o3*inv);
        sarr[4]=(short)f2b(o4*inv); sarr[5]=(short)f2b(o5*inv);
        sarr[6]=(short)f2b(o6*inv); sarr[7]=(short)f2b(o7*inv);
      }
      *(bf16x8*)&As[row][seg * 8] = *(bf16x8*)sarr;
    } else {
      bf16x8 av = (bf16x8)(short)0;
      if (gm < M) av = *(const bf16x8*)(A + (long)gm * Kstride + koff + k0 + seg * 8);
      *(bf16x8*)&As[row][seg * 8] = av;
    }
    *(bf16x8*)&Ws[row][seg * 8] =
      *(const bf16x8*)(W + (long)(bn + row) * Kstride + koff + k0 + seg * 8);
    __syncthreads();
    bf16x8 a0 = *(const bf16x8*)&As[wm * 32 + col][quad * 8];
    bf16x8 a1 = *(const bf16x8*)&As[wm * 32 + 16 + col][quad * 8];
    bf16x8 b0 = *(const bf16x8*)&Ws[wn * 32 + col][quad * 8];
    bf16x8 b1 = *(const bf16x8*)&Ws[wn * 32 + 16 + col][quad * 8];
    acc[0][0] = __builtin_amdgcn_mfma_f32_16x16x32_bf16(a0, b0, acc[0][0], 0, 0, 0);
    acc[0][1] = __builtin_amdgcn_mfma_f32_16x16x32_bf16(a0, b1, acc[0][1], 0, 0, 0);
    acc[1][0] = __builtin_amdgcn_mfma_f32_16x16x32_bf16(a1, b0, acc[1][0], 0, 0, 0);
    acc[1][1] = __builtin_amdgcn_mfma_f32_16x16x32_bf16(a1, b1, acc[1][1], 0, 0, 0);
  }
  #pragma unroll
  for (int i = 0; i < 2; i++)
    #pragma unroll
    for (int j = 0; j < 2; j++)
      #pragma unroll
      for (int r = 0; r < 4; r++){
        int gm = bm + wm * 32 + i * 16 + quad * 4 + r;
        if (gm >= M) continue;
        int gn = bn + wn * 32 + j * 16 + col;
        if (ATOM){
          float v = acc[i][j][r] + (blockIdx.z == 0 ? bs[gn] : 0.f);
          atomicAdd(&Cf[(long)gm * Nn + gn], v);
        } else {
          float v = acc[i][j][r] + bs[gn];
          if (ACT == 1) v = v * 0.5f * (1.0f + erff(v * 0.70710678118654752f));
          Cb[(long)gm * Nn + gn] = (short)f2b(v);
        }
      }
}

// ---- flash attention, fixed-shift softmax in exp2 domain — BARRIER-FREE.
// grid (33, H, NSPLIT); block = 4 waves x 16 rows. K, V and bias fragments are
// loaded DIRECTLY from global (L2-resident; 16x64B segments per instruction)
// with the permuted key mapping (sub-tile t4 = key j0+col*4+t4). Only the P
// C->A layout round-trip uses LDS, and that buffer is wave-private, so the
// tile loop has NO __syncthreads — waves run fully independently.
__global__ __launch_bounds__(256) void fattn_k(const short* __restrict__ Qb,
    const short* __restrict__ Kb, const short* __restrict__ Vtg,
    const unsigned char* __restrict__ bias8, float* __restrict__ Opart,
    float* __restrict__ Lpart){
  __shared__ __align__(16) short Ps[4][16][72];

  const int tid = threadIdx.x, wave = tid >> 6, lane = tid & 63;
  const int col = lane & 15, quad = lane >> 4;
  const int h = blockIdx.y, qz = blockIdx.z;
  const int i0 = blockIdx.x * 64 + wave * 16;
  const int t0 = (qz == 0) ? 0 : 9 + 8 * (qz - 1);   // 0,9,17,25
  const int t1 = t0 + ((qz == 0) ? 9 : 8);           // 33 tiles total

  int qrow = min(i0 + col, NF - 1);
  bf16x8 qf = *(const bf16x8*)(Qb + (long)qrow * D_ + h * HD_ + quad * 8);

  int brow[4];
  #pragma unroll
  for (int r = 0; r < 4; r++) brow[r] = min(i0 + quad * 4 + r, NF - 1);

  f32x4 oacc0 = {0.f, 0.f, 0.f, 0.f}, oacc1 = {0.f, 0.f, 0.f, 0.f};
  float rs[4] = {0.f, 0.f, 0.f, 0.f};
  const f32x4 zero4 = {0.f, 0.f, 0.f, 0.f};
  short* Pp = &Ps[wave][0][0];
  const short* Kh = Kb + h * HD_ + quad * 8;
  const short* Vh = Vtg + (long)(h * HD_) * BSTRIDE;

  for (int t = t0; t < t1; t++){
    const int j0 = t * 64;
    // K fragments direct from global (rows clamped; tail masked via p=0)
    f32x4 sacc[4];
    #pragma unroll
    for (int t4 = 0; t4 < 4; t4++){
      int j = min(j0 + col * 4 + t4, NF - 1);
      bf16x8 kf = *(const bf16x8*)(Kh + (long)j * D_);
      sacc[t4] = __builtin_amdgcn_mfma_f32_16x16x32_bf16(qf, kf, zero4, 0, 0, 0);
    }
    // bias: one coalesced dword per row (4 fp8 bytes for t4=0..3)
    unsigned bw[4];
    #pragma unroll
    for (int r = 0; r < 4; r++)
      bw[r] = *(const unsigned*)(bias8 + (long)(h * NF + brow[r]) * BSTRIDE + j0 + col * 4);

    const bool tail = (j0 + 64 > NF);
    #pragma unroll
    for (int r = 0; r < 4; r++){
      // fp8 byte-select must be a literal: decode all 4 bytes explicitly
      float bv0 = __builtin_amdgcn_cvt_f32_fp8((int)bw[r], 0);
      float bv1 = __builtin_amdgcn_cvt_f32_fp8((int)bw[r], 1);
      float bv2 = __builtin_amdgcn_cvt_f32_fp8((int)bw[r], 2);
      float bv3 = __builtin_amdgcn_cvt_f32_fp8((int)bw[r], 3);
      float bvv[4] = {bv0, bv1, bv2, bv3};
      unsigned short pb[4];
      #pragma unroll
      for (int t4 = 0; t4 < 4; t4++){
        float p = exp2f(sacc[t4][r] + bvv[t4]);   // Q pre-scaled by scale*log2e
        if (tail && (j0 + col * 4 + t4 >= NF)) p = 0.f;
        unsigned pu = __float_as_uint(p) & 0xffff0000u;  // RTZ to bf16
        rs[r] += __uint_as_float(pu);                    // consistent with PV
        pb[t4] = (unsigned short)(pu >> 16);
      }
      unsigned u0 = (unsigned)pb[0] | ((unsigned)pb[1] << 16);
      unsigned u1 = (unsigned)pb[2] | ((unsigned)pb[3] << 16);
      *(uint2*)&Pp[(quad * 4 + r) * 72 + col * 4] = make_uint2(u0, u1);
    }

    // PV: A = P (LDS, wave-private), B = V direct from pre-transposed global.
    // Tail keys have P=0, and Vtg pad rows are finite -> 0 contribution.
    #pragma unroll
    for (int ks = 0; ks < 2; ks++){
      bf16x8 af = *(const bf16x8*)&Pp[col * 72 + ks * 32 + quad * 8];
      bf16x8 v0 = *(const bf16x8*)(Vh + (long)col * BSTRIDE + j0 + ks * 32 + quad * 8);
      bf16x8 v1 = *(const bf16x8*)(Vh + (long)(16 + col) * BSTRIDE + j0 + ks * 32 + quad * 8);
      oacc0 = __builtin_amdgcn_mfma_f32_16x16x32_bf16(af, v0, oacc0, 0, 0, 0);
      oacc1 = __builtin_amdgcn_mfma_f32_16x16x32_bf16(af, v1, oacc1, 0, 0, 0);
    }
  }

  #pragma unroll
  for (int r = 0; r < 4; r++){
    #pragma unroll
    for (int o = 1; o < 16; o <<= 1) rs[r] += __shfl_xor(rs[r], o, 64);
  }
  long pi = ((long)qz * H_ + h) * RPAD + i0 + quad * 4;
  #pragma unroll
  for (int r = 0; r < 4; r++){
    Opart[(pi + r) * HD_ + col] = oacc0[r];
    Opart[(pi + r) * HD_ + 16 + col] = oacc1[r];
    if (col == 0) Lpart[pi + r] = rs[r];
  }
}

extern "C" void kernel_launch(void* const* d_in, const int* in_sizes, int n_in,
                              void* d_out, int out_size, void* d_ws, size_t ws_size,
                              hipStream_t stream){
  const float* x    = (const float*)d_in[0];
  const float* ea   = (const float*)d_in[1];
  const float* npw  = (const float*)d_in[2];
  const float* npb  = (const float*)d_in[3];
  const float* inE  = (const float*)d_in[4];
  const float* outE = (const float*)d_in[5];
  const float* db   = (const float*)d_in[6];
  const float* epw  = (const float*)d_in[7];
  const float* epb  = (const float*)d_in[8];
  const float* cls  = (const float*)d_in[9];
  const float* qw   = (const float*)d_in[10];
  const float* qb   = (const float*)d_in[11];
  const float* kw   = (const float*)d_in[12];
  const float* kb   = (const float*)d_in[13];
  const float* vw   = (const float*)d_in[14];
  const float* vb   = (const float*)d_in[15];
  const float* ow   = (const float*)d_in[16];
  const float* ob   = (const float*)d_in[17];
  const float* f1w  = (const float*)d_in[18];
  const float* f1b  = (const float*)d_in[19];
  const float* f2w  = (const float*)d_in[20];
  const float* f2bp = (const float*)d_in[21];
  const float* ln1s = (const float*)d_in[22];
  const float* ln1b = (const float*)d_in[23];
  const float* ln2s = (const float*)d_in[24];
  const float* ln2b = (const float*)d_in[25];
  const float* fns  = (const float*)d_in[26];
  const float* fnb  = (const float*)d_in[27];
  const int*   ei   = (const int*)d_in[28];
  const int*   dist = (const int*)d_in[29];

  float* ws = (float*)d_ws;
  long off = 0;
  float* h     = ws + off; off += (long)NF * D_;
  float* Opart = ws + off; off += (long)NSPLIT * H_ * RPAD * HD_;
  float* Lpart = ws + off; off += (long)NSPLIT * H_ * RPAD;
  unsigned char* bias8 = (unsigned char*)(ws + off);
  off += ((long)H_ * NF * BSTRIDE + 3) / 4;
  short* hnb   = (short*)(ws + off); off += ((long)NF * D_ + 1) / 2;
  short* QKb   = (short*)(ws + off); off += (long)NF * D_;      // Q then K
  short* Vtg   = (short*)(ws + off); off += ((long)D_ * BSTRIDE + 1) / 2;
  short* midb  = (short*)(ws + off); off += ((long)NF * FFN_ + 1) / 2;
  short* wqkv  = (short*)(ws + off); off += ((long)3 * L_ * D_ * D_ + 1) / 2;
  short* owb   = (short*)(ws + off); off += ((long)L_ * D_ * D_ + 1) / 2;
  short* f1wb  = (short*)(ws + off); off += ((long)L_ * FFN_ * D_ + 1) / 2;
  short* f2wb  = (short*)(ws + off); off += ((long)L_ * FFN_ * D_ + 1) / 2;
  int*   ind   = (int*)(ws + off);
  int*   outd  = ind + N_;

  zero_int<<<(2 * N_ + 255) / 256, 256, 0, stream>>>(ind, 2 * N_);
  deg_count<<<(E_ + 255) / 256, 256, 0, stream>>>(ei, ind, outd);
  embed_k<<<NF, D_, 0, stream>>>(x, npw, npb, inE, outE, ind, outd, cls, h);
  bias_fill<<<NF, 256, 0, stream>>>(dist, db, bias8);
  edge_bias<<<(E_ + 255) / 256, 256, 0, stream>>>(ea, epw, epb, ei, bias8);
  {
    long LFD = (long)L_ * FFN_ * D_;
    w2b_all<<<(int)((LFD + 255) / 256), 256, 0, stream>>>(qw, kw, vw, ow, f1w, f2w,
                                                          wqkv, owb, f1wb, f2wb);
  }

  dim3 gQKV((NF + 63) / 64, D_ / 64, 3);
  dim3 gO((NF + 63) / 64, D_ / 64, 2);
  dim3 gF((NF + 63) / 64, FFN_ / 64, 1);
  dim3 gF2((NF + 63) / 64, D_ / 64, 4);
  dim3 gA((NF + 63) / 64, H_, NSPLIT);
  for (int l = 0; l < L_; l++){
    ln_k<<<NF, D_, 0, stream>>>(h, ln1s + l * D_, ln1b + l * D_, nullptr, hnb, 0);
    qkv_gemm<<<gQKV, 256, 0, stream>>>(hnb, wqkv, qb + l * D_, kb + l * D_, vb + l * D_,
                                       QKb, Vtg, l);
    fattn_k<<<gA, 256, 0, stream>>>(QKb, QKb + (long)NF * D_, Vtg, bias8, Opart, Lpart);
    mgemm<0,1,1><<<gO, 256, 0, stream>>>(nullptr, Opart, Lpart,
                                         owb + (long)l * D_ * D_, ob + l * D_,
                                         h, nullptr, NF, D_, 128, D_);
    ln_k<<<NF, D_, 0, stream>>>(h, ln2s + l * D_, ln2b + l * D_, nullptr, hnb, 0);
    mgemm<1,0,0><<<gF, 256, 0, stream>>>(hnb, nullptr, nullptr,
                                         f1wb + (long)l * FFN_ * D_, f1b + l * FFN_,
                                         nullptr, midb, NF, FFN_, D_, D_);
    mgemm<0,1,0><<<gF2, 256, 0, stream>>>(midb, nullptr, nullptr,
                                          f2wb + (long)l * FFN_ * D_, f2bp + l * D_,
                                          h, nullptr, NF, D_, 256, FFN_);
  }
  ln_k<<<NF, D_, 0, stream>>>(h, fns, fnb, (float*)d_out, nullptr, 1);
}

// Round 13
// 710.371 us; speedup vs baseline: 1.1077x; 1.1077x over previous
//
#include <hip/hip_runtime.h>
#include <math.h>

#define N_ 2048
#define NF_IN 64
#define D_ 256
#define H_ 8
#define HD_ 32
#define L_ 6
#define FFN_ 1024
#define E_ 32768
#define EF_ 16
#define NF 2049      // N+1 tokens (CLS at row 0)
#define MAXDEG_ 64
#define BSTRIDE 2112 // padded row stride: bytes for fp8 bias, shorts for Vt
#define RPAD 2112    // padded row count for attention partials
#define NSPLIT 8     // key splits for flash attention (32 waves/CU resident)
#define LOG2E 1.4426950408889634f

typedef __attribute__((ext_vector_type(8))) short bf16x8;
typedef __attribute__((ext_vector_type(4))) float f32x4;

__device__ inline unsigned short f2b(float f){
  union { float f; unsigned u; } v; v.f = f;
  unsigned r = (v.u + 0x7fffu + ((v.u >> 16) & 1u)) >> 16;
  return (unsigned short)r;
}
__device__ inline float b2f(short s){
  union { unsigned u; float f; } v; v.u = ((unsigned)(unsigned short)s) << 16;
  return v.f;
}

// manual OCP e4m3fn encode, RNE (prep-path only)
__device__ inline unsigned char f2fp8(float f){
  unsigned u = __float_as_uint(f);
  unsigned s = (u >> 24) & 0x80u;
  float a = fabsf(f);
  if (a >= 448.f) return (unsigned char)(s | 0x7Eu);
  if (a < 0.015625f){                      // denormal region (incl. 0)
    int k = (int)rintf(a * 512.f);         // step 2^-9; k=8 rolls into 2^-6
    return (unsigned char)(s | (unsigned)k);
  }
  int e; float m = frexpf(a, &e);          // a = m*2^e, m in [0.5,1)
  int E = e - 1;
  int m3 = (int)rintf(m * 16.f) - 8;       // 0..8
  if (m3 == 8){ E++; m3 = 0; }
  if (E > 8){ E = 8; m3 = 6; }
  if (E == 8 && m3 > 6) m3 = 6;
  return (unsigned char)(s | (unsigned)((E + 7) << 3) | (unsigned)m3);
}
__device__ inline float fp82f(unsigned char b){
  return __builtin_amdgcn_cvt_f32_fp8((int)b, 0);
}

__device__ inline void atomic_add_fp8(unsigned char* p, float add){
  unsigned* wp = (unsigned*)((size_t)p & ~(size_t)3);
  int sh = (int)((size_t)p & 3) * 8;
  unsigned old = *wp, assumed;
  do {
    assumed = old;
    unsigned char cur = (unsigned char)((assumed >> sh) & 0xFFu);
    float f = fp82f(cur) + add;
    unsigned nw = (assumed & ~(0xFFu << sh)) | ((unsigned)f2fp8(f) << sh);
    old = atomicCAS(wp, assumed, nw);
  } while (old != assumed);
}

__device__ inline float wred_sum(float v){
  #pragma unroll
  for (int o = 32; o > 0; o >>= 1) v += __shfl_down(v, o, 64);
  return v;
}

__global__ void zero_int(int* p, int n){
  int i = blockIdx.x * blockDim.x + threadIdx.x;
  if (i < n) p[i] = 0;
}

__global__ void deg_count(const int* __restrict__ ei, int* __restrict__ ind,
                          int* __restrict__ outd){
  int e = blockIdx.x * blockDim.x + threadIdx.x;
  if (e >= E_) return;
  atomicAdd(&outd[ei[e]], 1);
  atomicAdd(&ind[ei[E_ + e]], 1);
}

__global__ void embed_k(const float* __restrict__ x, const float* __restrict__ W,
                        const float* __restrict__ b, const float* __restrict__ inE,
                        const float* __restrict__ outE, const int* __restrict__ ind,
                        const int* __restrict__ outd, const float* __restrict__ cls,
                        float* __restrict__ h){
  int i = blockIdx.x, d = threadIdx.x;
  if (i == 0){ h[d] = cls[d]; return; }
  int n = i - 1;
  const float4* xr = (const float4*)(x + (long)n * NF_IN);
  const float4* wr = (const float4*)(W + (long)d * NF_IN);
  float acc = b[d];
  #pragma unroll
  for (int k = 0; k < NF_IN / 4; k++){
    float4 a = xr[k], w = wr[k];
    acc += a.x * w.x + a.y * w.y + a.z * w.z + a.w * w.w;
  }
  int id = min(ind[n], MAXDEG_), od = min(outd[n], MAXDEG_);
  acc += inE[(long)id * D_ + d] + outE[(long)od * D_ + d];
  h[(long)i * D_ + d] = acc;
}

// bias stored as fp8 of (bias * log2e) — exp2-domain; grid NF
__global__ void bias_fill(const int* __restrict__ dist, const float* __restrict__ db,
                          unsigned char* __restrict__ bb){
  __shared__ unsigned char lut8[10][H_];
  int i = blockIdx.x;
  if (threadIdx.x < 80)
    ((unsigned char*)lut8)[threadIdx.x] = f2fp8(db[threadIdx.x] * LOG2E);
  __syncthreads();
  for (int u = threadIdx.x; u < BSTRIDE / 8; u += 256){
    int dp[8];
    #pragma unroll
    for (int k = 0; k < 8; k++){
      int j = u * 8 + k;
      int d = 0;
      if (i > 0 && j > 0 && j < NF){
        int dv = dist[(long)(i - 1) * N_ + (j - 1)];
        d = max(0, min(dv, 9));
      }
      dp[k] = (j < NF) ? d : -1;
    }
    #pragma unroll
    for (int h = 0; h < H_; h++){
      unsigned lo = 0, hi = 0;
      #pragma unroll
      for (int k = 0; k < 4; k++){
        unsigned b0 = (dp[k] >= 0) ? lut8[dp[k]][h] : 0u;
        unsigned b1 = (dp[4 + k] >= 0) ? lut8[dp[4 + k]][h] : 0u;
        lo |= b0 << (8 * k);
        hi |= b1 << (8 * k);
      }
      *(uint2*)(bb + ((long)h * NF + i) * BSTRIDE + u * 8) = make_uint2(lo, hi);
    }
  }
}

// sparse edge-feature bias: byte-CAS fp8 add (also log2e-scaled)
__global__ void edge_bias(const float* __restrict__ ea, const float* __restrict__ W,
                          const float* __restrict__ b, const int* __restrict__ ei,
                          unsigned char* __restrict__ bb){
  int e = blockIdx.x * blockDim.x + threadIdx.x;
  if (e >= E_) return;
  float a[EF_];
  #pragma unroll
  for (int k = 0; k < EF_; k++) a[k] = ea[(long)e * EF_ + k];
  int src = ei[e], dst = ei[E_ + e];
  #pragma unroll
  for (int h = 0; h < H_; h++){
    float p = b[h];
    #pragma unroll
    for (int k = 0; k < EF_; k++) p += a[k] * W[h * EF_ + k];
    atomic_add_fp8(bb + ((long)h * NF + src + 1) * BSTRIDE + (dst + 1), p * LOG2E);
  }
}

// all weight conversions in one dispatch
__global__ void w2b_all(const float* __restrict__ qw, const float* __restrict__ kw,
                        const float* __restrict__ vw, const float* __restrict__ ow,
                        const float* __restrict__ f1w, const float* __restrict__ f2w,
                        short* __restrict__ wqkv, short* __restrict__ owb,
                        short* __restrict__ f1wb, short* __restrict__ f2wb){
  long i = (long)blockIdx.x * 256 + threadIdx.x;
  const long DD = (long)D_ * D_, LDD = (long)L_ * DD, LFD = (long)L_ * FFN_ * D_;
  if (i < LDD){
    long l = i / DD, r = i - l * DD;
    wqkv[l * 3 * DD + r]          = (short)f2b(qw[i]);
    wqkv[l * 3 * DD + DD + r]     = (short)f2b(kw[i]);
    wqkv[l * 3 * DD + 2 * DD + r] = (short)f2b(vw[i]);
    owb[i] = (short)f2b(ow[i]);
  }
  if (i < LFD){
    f1wb[i] = (short)f2b(f1w[i]);
    f2wb[i] = (short)f2b(f2w[i]);
  }
}

__global__ void ln_k(const float* __restrict__ in, const float* __restrict__ s,
                     const float* __restrict__ b, float* __restrict__ outf,
                     short* __restrict__ outb, int dup0){
  __shared__ float r1[4], r2[4];
  int i = blockIdx.x, d = threadIdx.x;
  float v = in[(long)i * D_ + d];
  float s1 = wred_sum(v), s2 = wred_sum(v * v);
  if ((d & 63) == 0){ r1[d >> 6] = s1; r2[d >> 6] = s2; }
  __syncthreads();
  float S1 = r1[0] + r1[1] + r1[2] + r1[3];
  float S2 = r2[0] + r2[1] + r2[2] + r2[3];
  float m = S1 * (1.0f / D_);
  float var = S2 * (1.0f / D_) - m * m;
  float y = (v - m) * rsqrtf(var + 1e-5f) * s[d] + b[d];
  if (outf){
    outf[(long)i * D_ + d] = y;
    if (dup0 && i == 0) outf[(long)NF * D_ + d] = y;
  }
  if (outb) outb[(long)i * D_ + d] = (short)f2b(y);
}

// ---- fused QKV MFMA GEMM: grid (33, 4, 3). z==0 (Q) is pre-scaled by
// (1/sqrt(HD))*log2e so fattn's softmax works in the exp2 domain.
// z==2 (V): epilogue transposes the 64x64 tile through LDS so Vtg rows are
// written with coalesced 128B segments.
__global__ __launch_bounds__(256) void qkv_gemm(const short* __restrict__ A,
    const short* __restrict__ Wall, const float* __restrict__ qb,
    const float* __restrict__ kb, const float* __restrict__ vb,
    short* __restrict__ QKb, short* __restrict__ Vtg, int l){
  const int z = blockIdx.z;
  const short* W = Wall + ((long)(l * 3 + z)) * D_ * D_;
  const float* bsp = (z == 0) ? qb : (z == 1) ? kb : vb;
  __shared__ __align__(16) short As[64][40], Ws[64][40];
  __shared__ __align__(16) short Tt[64][72];   // V transpose buffer [dim][key]
  const int tid = threadIdx.x, lane = tid & 63, wave = tid >> 6;
  const int col = lane & 15, quad = lane >> 4;
  const int wm = wave & 1, wn = wave >> 1;
  const int bm = blockIdx.x * 64, bn = blockIdx.y * 64;
  const f32x4 zero4 = {0.f, 0.f, 0.f, 0.f};
  f32x4 acc[2][2] = {{zero4, zero4}, {zero4, zero4}};
  const int row = tid >> 2, seg = tid & 3;
  for (int k0 = 0; k0 < D_; k0 += 32){
    __syncthreads();
    bf16x8 av = (bf16x8)(short)0;
    int gm = bm + row;
    if (gm < NF) av = *(const bf16x8*)(A + (long)gm * D_ + k0 + seg * 8);
    *(bf16x8*)&As[row][seg * 8] = av;
    *(bf16x8*)&Ws[row][seg * 8] = *(const bf16x8*)(W + (long)(bn + row) * D_ + k0 + seg * 8);
    __syncthreads();
    bf16x8 a0 = *(const bf16x8*)&As[wm * 32 + col][quad * 8];
    bf16x8 a1 = *(const bf16x8*)&As[wm * 32 + 16 + col][quad * 8];
    bf16x8 b0 = *(const bf16x8*)&Ws[wn * 32 + col][quad * 8];
    bf16x8 b1 = *(const bf16x8*)&Ws[wn * 32 + 16 + col][quad * 8];
    acc[0][0] = __builtin_amdgcn_mfma_f32_16x16x32_bf16(a0, b0, acc[0][0], 0, 0, 0);
    acc[0][1] = __builtin_amdgcn_mfma_f32_16x16x32_bf16(a0, b1, acc[0][1], 0, 0, 0);
    acc[1][0] = __builtin_amdgcn_mfma_f32_16x16x32_bf16(a1, b0, acc[1][0], 0, 0, 0);
    acc[1][1] = __builtin_amdgcn_mfma_f32_16x16x32_bf16(a1, b1, acc[1][1], 0, 0, 0);
  }
  if (z < 2){
    const float qscale = 0.25501133194822025f;  // (1/sqrt(32)) * log2e
    #pragma unroll
    for (int i = 0; i < 2; i++)
      #pragma unroll
      for (int j = 0; j < 2; j++)
        #pragma unroll
        for (int r = 0; r < 4; r++){
          int gm = bm + wm * 32 + i * 16 + quad * 4 + r;
          if (gm >= NF) continue;
          int gn = bn + wn * 32 + j * 16 + col;
          float v = acc[i][j][r] + bsp[gn];
          if (z == 0) v *= qscale;
          QKb[(long)z * NF * D_ + (long)gm * D_ + gn] = (short)f2b(v);
        }
  } else {
    // transpose tile into LDS: Tt[dim][key]; rows gm>=NF hold finite values
    #pragma unroll
    for (int i = 0; i < 2; i++)
      #pragma unroll
      for (int j = 0; j < 2; j++){
        int ln_ = wn * 32 + j * 16 + col;     // local dim
        int lc = wm * 32 + i * 16 + quad * 4; // local key base (4 consecutive)
        float bsv = bsp[bn + ln_];
        short pk[4];
        #pragma unroll
        for (int r = 0; r < 4; r++) pk[r] = (short)f2b(acc[i][j][r] + bsv);
        *(short4*)&Tt[ln_][lc] = *(short4*)pk;
      }
    __syncthreads();
    int lr = tid >> 2, sg = tid & 3;
    bf16x8 v0 = *(const bf16x8*)&Tt[lr][sg * 16];
    bf16x8 v1 = *(const bf16x8*)&Tt[lr][sg * 16 + 8];
    short* dstp = Vtg + (long)(bn + lr) * BSTRIDE + bm + sg * 16;
    *(bf16x8*)dstp = v0;
    *(bf16x8*)(dstp + 8) = v1;
  }
}

// ---- generic MFMA GEMM.
// MERGE=1: A[gm][k] = (sum_q Opart[q][k/32][gm][k%32]) / (sum_q Lpart[q][k/32][gm])
// ATOM=1: atomicAdd partial into Cf (bias added by z==0 block); else bf16 out + ACT.
template<int ACT, int ATOM, int MERGE>
__global__ __launch_bounds__(256) void mgemm(const short* __restrict__ A,
    const float* __restrict__ Op, const float* __restrict__ Lp,
    const short* __restrict__ W, const float* __restrict__ bs,
    float* __restrict__ Cf, short* __restrict__ Cb,
    int M, int Nn, int Kc, int Kstride){
  __shared__ __align__(16) short As[64][40], Ws[64][40];
  const int tid = threadIdx.x, lane = tid & 63, wave = tid >> 6;
  const int col = lane & 15, quad = lane >> 4;
  const int wm = wave & 1, wn = wave >> 1;
  const int bm = blockIdx.x * 64, bn = blockIdx.y * 64;
  const int koff = blockIdx.z * Kc;
  const f32x4 zero4 = {0.f, 0.f, 0.f, 0.f};
  f32x4 acc[2][2] = {{zero4, zero4}, {zero4, zero4}};
  const int row = tid >> 2, seg = tid & 3;
  for (int k0 = 0; k0 < Kc; k0 += 32){
    __syncthreads();
    int gm = bm + row;
    if (MERGE){
      int kg = koff + k0 + seg * 8;
      int hh = kg >> 5, d0 = kg & 31;
      short sarr[8] = {0,0,0,0,0,0,0,0};
      if (gm < M){
        float o0=0,o1=0,o2=0,o3=0,o4=0,o5=0,o6=0,o7=0, sl=0.f;
        #pragma unroll
        for (int q = 0; q < NSPLIT; q++){
          long rb = (long)(q * H_ + hh) * RPAD + gm;
          const float* op = Op + rb * HD_ + d0;
          float4 v0 = *(const float4*)op, v1 = *(const float4*)(op + 4);
          o0 += v0.x; o1 += v0.y; o2 += v0.z; o3 += v0.w;
          o4 += v1.x; o5 += v1.y; o6 += v1.z; o7 += v1.w;
          sl += Lp[rb];
        }
        float inv = 1.0f / sl;
        sarr[0]=(short)f2b(o0*inv); sarr[1]=(short)f2b(o1*inv);
        sarr[2]=(short)f2b(o2*inv); sarr[3]=(short)f2b(o3*inv);
        sarr[4]=(short)f2b(o4*inv); sarr[5]=(short)f2b(o5*inv);
        sarr[6]=(short)f2b(o6*inv); sarr[7]=(short)f2b(o7*inv);
      }
      *(bf16x8*)&As[row][seg * 8] = *(bf16x8*)sarr;
    } else {
      bf16x8 av = (bf16x8)(short)0;
      if (gm < M) av = *(const bf16x8*)(A + (long)gm * Kstride + koff + k0 + seg * 8);
      *(bf16x8*)&As[row][seg * 8] = av;
    }
    *(bf16x8*)&Ws[row][seg * 8] =
      *(const bf16x8*)(W + (long)(bn + row) * Kstride + koff + k0 + seg * 8);
    __syncthreads();
    bf16x8 a0 = *(const bf16x8*)&As[wm * 32 + col][quad * 8];
    bf16x8 a1 = *(const bf16x8*)&As[wm * 32 + 16 + col][quad * 8];
    bf16x8 b0 = *(const bf16x8*)&Ws[wn * 32 + col][quad * 8];
    bf16x8 b1 = *(const bf16x8*)&Ws[wn * 32 + 16 + col][quad * 8];
    acc[0][0] = __builtin_amdgcn_mfma_f32_16x16x32_bf16(a0, b0, acc[0][0], 0, 0, 0);
    acc[0][1] = __builtin_amdgcn_mfma_f32_16x16x32_bf16(a0, b1, acc[0][1], 0, 0, 0);
    acc[1][0] = __builtin_amdgcn_mfma_f32_16x16x32_bf16(a1, b0, acc[1][0], 0, 0, 0);
    acc[1][1] = __builtin_amdgcn_mfma_f32_16x16x32_bf16(a1, b1, acc[1][1], 0, 0, 0);
  }
  #pragma unroll
  for (int i = 0; i < 2; i++)
    #pragma unroll
    for (int j = 0; j < 2; j++)
      #pragma unroll
      for (int r = 0; r < 4; r++){
        int gm = bm + wm * 32 + i * 16 + quad * 4 + r;
        if (gm >= M) continue;
        int gn = bn + wn * 32 + j * 16 + col;
        if (ATOM){
          float v = acc[i][j][r] + (blockIdx.z == 0 ? bs[gn] : 0.f);
          atomicAdd(&Cf[(long)gm * Nn + gn], v);
        } else {
          float v = acc[i][j][r] + bs[gn];
          if (ACT == 1) v = v * 0.5f * (1.0f + erff(v * 0.70710678118654752f));
          Cb[(long)gm * Nn + gn] = (short)f2b(v);
        }
      }
}

// ---- flash attention, fixed-shift softmax in exp2 domain.
// grid (33, H, NSPLIT); block = 4 waves x 16 rows.
// Key permutation: MFMA sub-tile t4 covers key j0 + col*4 + t4, so each lane's
// 4 bias bytes per row are ONE coalesced global dword, and P is written with
// packed ds_write_b64. K/V staged in LDS (r12 showed direct-global feeding
// regresses: L2 latency lands in the serial per-wave chain).
__global__ __launch_bounds__(256) void fattn_k(const short* __restrict__ Qb,
    const short* __restrict__ Kb, const short* __restrict__ Vtg,
    const unsigned char* __restrict__ bias8, float* __restrict__ Opart,
    float* __restrict__ Lpart){
  __shared__ __align__(16) short Ks[64][42];   // stride 42: 2-way max on permuted reads
  __shared__ __align__(16) short Vt[32][72];
  __shared__ __align__(16) short Ps[4][16][72];

  const int tid = threadIdx.x, wave = tid >> 6, lane = tid & 63;
  const int col = lane & 15, quad = lane >> 4;
  const int h = blockIdx.y, qz = blockIdx.z;
  const int i0 = blockIdx.x * 64 + wave * 16;
  const int t0 = (qz == 0) ? 0 : 5 + 4 * (qz - 1);   // 0,5,9,...,29
  const int t1 = t0 + ((qz == 0) ? 5 : 4);           // 33 tiles total

  int qrow = min(i0 + col, NF - 1);
  bf16x8 qf = *(const bf16x8*)(Qb + (long)qrow * D_ + h * HD_ + quad * 8);

  int brow[4];
  #pragma unroll
  for (int r = 0; r < 4; r++) brow[r] = min(i0 + quad * 4 + r, NF - 1);

  f32x4 oacc0 = {0.f, 0.f, 0.f, 0.f}, oacc1 = {0.f, 0.f, 0.f, 0.f};
  float rs[4] = {0.f, 0.f, 0.f, 0.f};
  const f32x4 zero4 = {0.f, 0.f, 0.f, 0.f};
  short* Pp = &Ps[wave][0][0];

  for (int t = t0; t < t1; t++){
    const int j0 = t * 64;
    // bias: one dword per row (4 fp8 bytes for t4=0..3), coalesced across col
    unsigned bw[4];
    #pragma unroll
    for (int r = 0; r < 4; r++)
      bw[r] = *(const unsigned*)(bias8 + (long)(h * NF + brow[r]) * BSTRIDE + j0 + col * 4);
    __syncthreads();
    { // K tile: 64 keys x 32 dims
      int key = tid >> 2, seg = tid & 3;
      int j = j0 + key;
      bf16x8 kv = (bf16x8)(short)0;
      if (j < NF) kv = *(const bf16x8*)(Kb + (long)j * D_ + h * HD_ + seg * 8);
      *(bf16x8*)&Ks[key][seg * 8] = kv;
    }
    { // V tile (pre-transposed): 32 dims x 64 keys
      int d = tid >> 3, seg = tid & 7;
      *(bf16x8*)&Vt[d][seg * 8] =
        *(const bf16x8*)(Vtg + (long)(h * HD_ + d) * BSTRIDE + j0 + seg * 8);
    }
    __syncthreads();

    f32x4 sacc[4];
    #pragma unroll
    for (int t4 = 0; t4 < 4; t4++){
      bf16x8 kf = *(const bf16x8*)&Ks[col * 4 + t4][quad * 8];
      sacc[t4] = __builtin_amdgcn_mfma_f32_16x16x32_bf16(qf, kf, zero4, 0, 0, 0);
    }

    const bool tail = (j0 + 64 > NF);
    #pragma unroll
    for (int r = 0; r < 4; r++){
      // fp8 byte-select must be a literal: decode all 4 bytes explicitly
      float bv0 = __builtin_amdgcn_cvt_f32_fp8((int)bw[r], 0);
      float bv1 = __builtin_amdgcn_cvt_f32_fp8((int)bw[r], 1);
      float bv2 = __builtin_amdgcn_cvt_f32_fp8((int)bw[r], 2);
      float bv3 = __builtin_amdgcn_cvt_f32_fp8((int)bw[r], 3);
      float bvv[4] = {bv0, bv1, bv2, bv3};
      unsigned short pb[4];
      #pragma unroll
      for (int t4 = 0; t4 < 4; t4++){
        float p = exp2f(sacc[t4][r] + bvv[t4]);   // Q pre-scaled by scale*log2e
        if (tail && (j0 + col * 4 + t4 >= NF)) p = 0.f;
        unsigned pu = __float_as_uint(p) & 0xffff0000u;  // RTZ to bf16
        rs[r] += __uint_as_float(pu);                    // consistent with PV
        pb[t4] = (unsigned short)(pu >> 16);
      }
      unsigned u0 = (unsigned)pb[0] | ((unsigned)pb[1] << 16);
      unsigned u1 = (unsigned)pb[2] | ((unsigned)pb[3] << 16);
      *(uint2*)&Pp[(quad * 4 + r) * 72 + col * 4] = make_uint2(u0, u1);
    }

    #pragma unroll
    for (int ks = 0; ks < 2; ks++){
      bf16x8 af = *(const bf16x8*)&Pp[col * 72 + ks * 32 + quad * 8];
      bf16x8 v0 = *(const bf16x8*)&Vt[col][ks * 32 + quad * 8];
      bf16x8 v1 = *(const bf16x8*)&Vt[16 + col][ks * 32 + quad * 8];
      oacc0 = __builtin_amdgcn_mfma_f32_16x16x32_bf16(af, v0, oacc0, 0, 0, 0);
      oacc1 = __builtin_amdgcn_mfma_f32_16x16x32_bf16(af, v1, oacc1, 0, 0, 0);
    }
  }

  #pragma unroll
  for (int r = 0; r < 4; r++){
    #pragma unroll
    for (int o = 1; o < 16; o <<= 1) rs[r] += __shfl_xor(rs[r], o, 64);
  }
  long pi = ((long)qz * H_ + h) * RPAD + i0 + quad * 4;
  #pragma unroll
  for (int r = 0; r < 4; r++){
    Opart[(pi + r) * HD_ + col] = oacc0[r];
    Opart[(pi + r) * HD_ + 16 + col] = oacc1[r];
    if (col == 0) Lpart[pi + r] = rs[r];
  }
}

extern "C" void kernel_launch(void* const* d_in, const int* in_sizes, int n_in,
                              void* d_out, int out_size, void* d_ws, size_t ws_size,
                              hipStream_t stream){
  const float* x    = (const float*)d_in[0];
  const float* ea   = (const float*)d_in[1];
  const float* npw  = (const float*)d_in[2];
  const float* npb  = (const float*)d_in[3];
  const float* inE  = (const float*)d_in[4];
  const float* outE = (const float*)d_in[5];
  const float* db   = (const float*)d_in[6];
  const float* epw  = (const float*)d_in[7];
  const float* epb  = (const float*)d_in[8];
  const float* cls  = (const float*)d_in[9];
  const float* qw   = (const float*)d_in[10];
  const float* qb   = (const float*)d_in[11];
  const float* kw   = (const float*)d_in[12];
  const float* kb   = (const float*)d_in[13];
  const float* vw   = (const float*)d_in[14];
  const float* vb   = (const float*)d_in[15];
  const float* ow   = (const float*)d_in[16];
  const float* ob   = (const float*)d_in[17];
  const float* f1w  = (const float*)d_in[18];
  const float* f1b  = (const float*)d_in[19];
  const float* f2w  = (const float*)d_in[20];
  const float* f2bp = (const float*)d_in[21];
  const float* ln1s = (const float*)d_in[22];
  const float* ln1b = (const float*)d_in[23];
  const float* ln2s = (const float*)d_in[24];
  const float* ln2b = (const float*)d_in[25];
  const float* fns  = (const float*)d_in[26];
  const float* fnb  = (const float*)d_in[27];
  const int*   ei   = (const int*)d_in[28];
  const int*   dist = (const int*)d_in[29];

  float* ws = (float*)d_ws;
  long off = 0;
  float* h     = ws + off; off += (long)NF * D_;
  float* Opart = ws + off; off += (long)NSPLIT * H_ * RPAD * HD_;
  float* Lpart = ws + off; off += (long)NSPLIT * H_ * RPAD;
  unsigned char* bias8 = (unsigned char*)(ws + off);
  off += ((long)H_ * NF * BSTRIDE + 3) / 4;
  short* hnb   = (short*)(ws + off); off += ((long)NF * D_ + 1) / 2;
  short* QKb   = (short*)(ws + off); off += (long)NF * D_;      // Q then K
  short* Vtg   = (short*)(ws + off); off += ((long)D_ * BSTRIDE + 1) / 2;
  short* midb  = (short*)(ws + off); off += ((long)NF * FFN_ + 1) / 2;
  short* wqkv  = (short*)(ws + off); off += ((long)3 * L_ * D_ * D_ + 1) / 2;
  short* owb   = (short*)(ws + off); off += ((long)L_ * D_ * D_ + 1) / 2;
  short* f1wb  = (short*)(ws + off); off += ((long)L_ * FFN_ * D_ + 1) / 2;
  short* f2wb  = (short*)(ws + off); off += ((long)L_ * FFN_ * D_ + 1) / 2;
  int*   ind   = (int*)(ws + off);
  int*   outd  = ind + N_;

  zero_int<<<(2 * N_ + 255) / 256, 256, 0, stream>>>(ind, 2 * N_);
  deg_count<<<(E_ + 255) / 256, 256, 0, stream>>>(ei, ind, outd);
  embed_k<<<NF, D_, 0, stream>>>(x, npw, npb, inE, outE, ind, outd, cls, h);
  bias_fill<<<NF, 256, 0, stream>>>(dist, db, bias8);
  edge_bias<<<(E_ + 255) / 256, 256, 0, stream>>>(ea, epw, epb, ei, bias8);
  {
    long LFD = (long)L_ * FFN_ * D_;
    w2b_all<<<(int)((LFD + 255) / 256), 256, 0, stream>>>(qw, kw, vw, ow, f1w, f2w,
                                                          wqkv, owb, f1wb, f2wb);
  }

  dim3 gQKV((NF + 63) / 64, D_ / 64, 3);
  dim3 gO((NF + 63) / 64, D_ / 64, 2);
  dim3 gF((NF + 63) / 64, FFN_ / 64, 1);
  dim3 gF2((NF + 63) / 64, D_ / 64, 4);
  dim3 gA((NF + 63) / 64, H_, NSPLIT);
  for (int l = 0; l < L_; l++){
    ln_k<<<NF, D_, 0, stream>>>(h, ln1s + l * D_, ln1b + l * D_, nullptr, hnb, 0);
    qkv_gemm<<<gQKV, 256, 0, stream>>>(hnb, wqkv, qb + l * D_, kb + l * D_, vb + l * D_,
                                       QKb, Vtg, l);
    fattn_k<<<gA, 256, 0, stream>>>(QKb, QKb + (long)NF * D_, Vtg, bias8, Opart, Lpart);
    mgemm<0,1,1><<<gO, 256, 0, stream>>>(nullptr, Opart, Lpart,
                                         owb + (long)l * D_ * D_, ob + l * D_,
                                         h, nullptr, NF, D_, 128, D_);
    ln_k<<<NF, D_, 0, stream>>>(h, ln2s + l * D_, ln2b + l * D_, nullptr, hnb, 0);
    mgemm<1,0,0><<<gF, 256, 0, stream>>>(hnb, nullptr, nullptr,
                                         f1wb + (long)l * FFN_ * D_, f1b + l * FFN_,
                                         nullptr, midb, NF, FFN_, D_, D_);
    mgemm<0,1,0><<<gF2, 256, 0, stream>>>(midb, nullptr, nullptr,
                                          f2wb + (long)l * FFN_ * D_, f2bp + l * D_,
                                          h, nullptr, NF, D_, 256, FFN_);
  }
  ln_k<<<NF, D_, 0, stream>>>(h, fns, fnb, (float*)d_out, nullptr, 1);
}

// Round 14
// 683.642 us; speedup vs baseline: 1.1510x; 1.0391x over previous
//
#include <hip/hip_runtime.h>
#include <math.h>

#define N_ 2048
#define NF_IN 64
#define D_ 256
#define H_ 8
#define HD_ 32
#define L_ 6
#define FFN_ 1024
#define E_ 32768
#define EF_ 16
#define NF 2049      // N+1 tokens (CLS at row 0)
#define MAXDEG_ 64
#define BSTRIDE 2112 // padded row stride: bytes for fp8 bias, shorts for Vt
#define RPAD 2112    // padded row count for attention partials
#define NSPLIT 4     // key splits for flash attention (r11 best; 8 regressed)
#define LOG2E 1.4426950408889634f

typedef __attribute__((ext_vector_type(8))) short bf16x8;
typedef __attribute__((ext_vector_type(4))) float f32x4;

__device__ inline unsigned short f2b(float f){
  union { float f; unsigned u; } v; v.f = f;
  unsigned r = (v.u + 0x7fffu + ((v.u >> 16) & 1u)) >> 16;
  return (unsigned short)r;
}
__device__ inline float b2f(short s){
  union { unsigned u; float f; } v; v.u = ((unsigned)(unsigned short)s) << 16;
  return v.f;
}

// manual OCP e4m3fn encode, RNE (prep-path only)
__device__ inline unsigned char f2fp8(float f){
  unsigned u = __float_as_uint(f);
  unsigned s = (u >> 24) & 0x80u;
  float a = fabsf(f);
  if (a >= 448.f) return (unsigned char)(s | 0x7Eu);
  if (a < 0.015625f){                      // denormal region (incl. 0)
    int k = (int)rintf(a * 512.f);         // step 2^-9; k=8 rolls into 2^-6
    return (unsigned char)(s | (unsigned)k);
  }
  int e; float m = frexpf(a, &e);          // a = m*2^e, m in [0.5,1)
  int E = e - 1;
  int m3 = (int)rintf(m * 16.f) - 8;       // 0..8
  if (m3 == 8){ E++; m3 = 0; }
  if (E > 8){ E = 8; m3 = 6; }
  if (E == 8 && m3 > 6) m3 = 6;
  return (unsigned char)(s | (unsigned)((E + 7) << 3) | (unsigned)m3);
}
__device__ inline float fp82f(unsigned char b){
  return __builtin_amdgcn_cvt_f32_fp8((int)b, 0);
}

__device__ inline void atomic_add_fp8(unsigned char* p, float add){
  unsigned* wp = (unsigned*)((size_t)p & ~(size_t)3);
  int sh = (int)((size_t)p & 3) * 8;
  unsigned old = *wp, assumed;
  do {
    assumed = old;
    unsigned char cur = (unsigned char)((assumed >> sh) & 0xFFu);
    float f = fp82f(cur) + add;
    unsigned nw = (assumed & ~(0xFFu << sh)) | ((unsigned)f2fp8(f) << sh);
    old = atomicCAS(wp, assumed, nw);
  } while (old != assumed);
}

__device__ inline float wred_sum(float v){
  #pragma unroll
  for (int o = 32; o > 0; o >>= 1) v += __shfl_down(v, o, 64);
  return v;
}

__global__ void zero_int(int* p, int n){
  int i = blockIdx.x * blockDim.x + threadIdx.x;
  if (i < n) p[i] = 0;
}

__global__ void deg_count(const int* __restrict__ ei, int* __restrict__ ind,
                          int* __restrict__ outd){
  int e = blockIdx.x * blockDim.x + threadIdx.x;
  if (e >= E_) return;
  atomicAdd(&outd[ei[e]], 1);
  atomicAdd(&ind[ei[E_ + e]], 1);
}

__global__ void embed_k(const float* __restrict__ x, const float* __restrict__ W,
                        const float* __restrict__ b, const float* __restrict__ inE,
                        const float* __restrict__ outE, const int* __restrict__ ind,
                        const int* __restrict__ outd, const float* __restrict__ cls,
                        float* __restrict__ h){
  int i = blockIdx.x, d = threadIdx.x;
  if (i == 0){ h[d] = cls[d]; return; }
  int n = i - 1;
  const float4* xr = (const float4*)(x + (long)n * NF_IN);
  const float4* wr = (const float4*)(W + (long)d * NF_IN);
  float acc = b[d];
  #pragma unroll
  for (int k = 0; k < NF_IN / 4; k++){
    float4 a = xr[k], w = wr[k];
    acc += a.x * w.x + a.y * w.y + a.z * w.z + a.w * w.w;
  }
  int id = min(ind[n], MAXDEG_), od = min(outd[n], MAXDEG_);
  acc += inE[(long)id * D_ + d] + outE[(long)od * D_ + d];
  h[(long)i * D_ + d] = acc;
}

// bias stored as fp8 of (bias * log2e) — exp2-domain; grid NF
__global__ void bias_fill(const int* __restrict__ dist, const float* __restrict__ db,
                          unsigned char* __restrict__ bb){
  __shared__ unsigned char lut8[10][H_];
  int i = blockIdx.x;
  if (threadIdx.x < 80)
    ((unsigned char*)lut8)[threadIdx.x] = f2fp8(db[threadIdx.x] * LOG2E);
  __syncthreads();
  for (int u = threadIdx.x; u < BSTRIDE / 8; u += 256){
    int dp[8];
    #pragma unroll
    for (int k = 0; k < 8; k++){
      int j = u * 8 + k;
      int d = 0;
      if (i > 0 && j > 0 && j < NF){
        int dv = dist[(long)(i - 1) * N_ + (j - 1)];
        d = max(0, min(dv, 9));
      }
      dp[k] = (j < NF) ? d : -1;
    }
    #pragma unroll
    for (int h = 0; h < H_; h++){
      unsigned lo = 0, hi = 0;
      #pragma unroll
      for (int k = 0; k < 4; k++){
        unsigned b0 = (dp[k] >= 0) ? lut8[dp[k]][h] : 0u;
        unsigned b1 = (dp[4 + k] >= 0) ? lut8[dp[4 + k]][h] : 0u;
        lo |= b0 << (8 * k);
        hi |= b1 << (8 * k);
      }
      *(uint2*)(bb + ((long)h * NF + i) * BSTRIDE + u * 8) = make_uint2(lo, hi);
    }
  }
}

// sparse edge-feature bias: byte-CAS fp8 add (also log2e-scaled)
__global__ void edge_bias(const float* __restrict__ ea, const float* __restrict__ W,
                          const float* __restrict__ b, const int* __restrict__ ei,
                          unsigned char* __restrict__ bb){
  int e = blockIdx.x * blockDim.x + threadIdx.x;
  if (e >= E_) return;
  float a[EF_];
  #pragma unroll
  for (int k = 0; k < EF_; k++) a[k] = ea[(long)e * EF_ + k];
  int src = ei[e], dst = ei[E_ + e];
  #pragma unroll
  for (int h = 0; h < H_; h++){
    float p = b[h];
    #pragma unroll
    for (int k = 0; k < EF_; k++) p += a[k] * W[h * EF_ + k];
    atomic_add_fp8(bb + ((long)h * NF + src + 1) * BSTRIDE + (dst + 1), p * LOG2E);
  }
}

// all weight conversions in one dispatch
__global__ void w2b_all(const float* __restrict__ qw, const float* __restrict__ kw,
                        const float* __restrict__ vw, const float* __restrict__ ow,
                        const float* __restrict__ f1w, const float* __restrict__ f2w,
                        short* __restrict__ wqkv, short* __restrict__ owb,
                        short* __restrict__ f1wb, short* __restrict__ f2wb){
  long i = (long)blockIdx.x * 256 + threadIdx.x;
  const long DD = (long)D_ * D_, LDD = (long)L_ * DD, LFD = (long)L_ * FFN_ * D_;
  if (i < LDD){
    long l = i / DD, r = i - l * DD;
    wqkv[l * 3 * DD + r]          = (short)f2b(qw[i]);
    wqkv[l * 3 * DD + DD + r]     = (short)f2b(kw[i]);
    wqkv[l * 3 * DD + 2 * DD + r] = (short)f2b(vw[i]);
    owb[i] = (short)f2b(ow[i]);
  }
  if (i < LFD){
    f1wb[i] = (short)f2b(f1w[i]);
    f2wb[i] = (short)f2b(f2w[i]);
  }
}

__global__ void ln_k(const float* __restrict__ in, const float* __restrict__ s,
                     const float* __restrict__ b, float* __restrict__ outf,
                     short* __restrict__ outb, int dup0){
  __shared__ float r1[4], r2[4];
  int i = blockIdx.x, d = threadIdx.x;
  float v = in[(long)i * D_ + d];
  float s1 = wred_sum(v), s2 = wred_sum(v * v);
  if ((d & 63) == 0){ r1[d >> 6] = s1; r2[d >> 6] = s2; }
  __syncthreads();
  float S1 = r1[0] + r1[1] + r1[2] + r1[3];
  float S2 = r2[0] + r2[1] + r2[2] + r2[3];
  float m = S1 * (1.0f / D_);
  float var = S2 * (1.0f / D_) - m * m;
  float y = (v - m) * rsqrtf(var + 1e-5f) * s[d] + b[d];
  if (outf){
    outf[(long)i * D_ + d] = y;
    if (dup0 && i == 0) outf[(long)NF * D_ + d] = y;
  }
  if (outb) outb[(long)i * D_ + d] = (short)f2b(y);
}

// ---- fused QKV MFMA GEMM: grid (33, 4, 3). z==0 (Q) is pre-scaled by
// (1/sqrt(HD))*log2e so fattn's softmax works in the exp2 domain.
// z==2 (V): epilogue transposes the 64x64 tile through LDS so Vtg rows are
// written with coalesced 128B segments.
__global__ __launch_bounds__(256) void qkv_gemm(const short* __restrict__ A,
    const short* __restrict__ Wall, const float* __restrict__ qb,
    const float* __restrict__ kb, const float* __restrict__ vb,
    short* __restrict__ QKb, short* __restrict__ Vtg, int l){
  const int z = blockIdx.z;
  const short* W = Wall + ((long)(l * 3 + z)) * D_ * D_;
  const float* bsp = (z == 0) ? qb : (z == 1) ? kb : vb;
  __shared__ __align__(16) short As[64][40], Ws[64][40];
  __shared__ __align__(16) short Tt[64][72];   // V transpose buffer [dim][key]
  const int tid = threadIdx.x, lane = tid & 63, wave = tid >> 6;
  const int col = lane & 15, quad = lane >> 4;
  const int wm = wave & 1, wn = wave >> 1;
  const int bm = blockIdx.x * 64, bn = blockIdx.y * 64;
  const f32x4 zero4 = {0.f, 0.f, 0.f, 0.f};
  f32x4 acc[2][2] = {{zero4, zero4}, {zero4, zero4}};
  const int row = tid >> 2, seg = tid & 3;
  for (int k0 = 0; k0 < D_; k0 += 32){
    __syncthreads();
    bf16x8 av = (bf16x8)(short)0;
    int gm = bm + row;
    if (gm < NF) av = *(const bf16x8*)(A + (long)gm * D_ + k0 + seg * 8);
    *(bf16x8*)&As[row][seg * 8] = av;
    *(bf16x8*)&Ws[row][seg * 8] = *(const bf16x8*)(W + (long)(bn + row) * D_ + k0 + seg * 8);
    __syncthreads();
    bf16x8 a0 = *(const bf16x8*)&As[wm * 32 + col][quad * 8];
    bf16x8 a1 = *(const bf16x8*)&As[wm * 32 + 16 + col][quad * 8];
    bf16x8 b0 = *(const bf16x8*)&Ws[wn * 32 + col][quad * 8];
    bf16x8 b1 = *(const bf16x8*)&Ws[wn * 32 + 16 + col][quad * 8];
    acc[0][0] = __builtin_amdgcn_mfma_f32_16x16x32_bf16(a0, b0, acc[0][0], 0, 0, 0);
    acc[0][1] = __builtin_amdgcn_mfma_f32_16x16x32_bf16(a0, b1, acc[0][1], 0, 0, 0);
    acc[1][0] = __builtin_amdgcn_mfma_f32_16x16x32_bf16(a1, b0, acc[1][0], 0, 0, 0);
    acc[1][1] = __builtin_amdgcn_mfma_f32_16x16x32_bf16(a1, b1, acc[1][1], 0, 0, 0);
  }
  if (z < 2){
    const float qscale = 0.25501133194822025f;  // (1/sqrt(32)) * log2e
    #pragma unroll
    for (int i = 0; i < 2; i++)
      #pragma unroll
      for (int j = 0; j < 2; j++)
        #pragma unroll
        for (int r = 0; r < 4; r++){
          int gm = bm + wm * 32 + i * 16 + quad * 4 + r;
          if (gm >= NF) continue;
          int gn = bn + wn * 32 + j * 16 + col;
          float v = acc[i][j][r] + bsp[gn];
          if (z == 0) v *= qscale;
          QKb[(long)z * NF * D_ + (long)gm * D_ + gn] = (short)f2b(v);
        }
  } else {
    // transpose tile into LDS: Tt[dim][key]; rows gm>=NF hold finite values
    #pragma unroll
    for (int i = 0; i < 2; i++)
      #pragma unroll
      for (int j = 0; j < 2; j++){
        int ln_ = wn * 32 + j * 16 + col;     // local dim
        int lc = wm * 32 + i * 16 + quad * 4; // local key base (4 consecutive)
        float bsv = bsp[bn + ln_];
        short pk[4];
        #pragma unroll
        for (int r = 0; r < 4; r++) pk[r] = (short)f2b(acc[i][j][r] + bsv);
        *(short4*)&Tt[ln_][lc] = *(short4*)pk;
      }
    __syncthreads();
    int lr = tid >> 2, sg = tid & 3;
    bf16x8 v0 = *(const bf16x8*)&Tt[lr][sg * 16];
    bf16x8 v1 = *(const bf16x8*)&Tt[lr][sg * 16 + 8];
    short* dstp = Vtg + (long)(bn + lr) * BSTRIDE + bm + sg * 16;
    *(bf16x8*)dstp = v0;
    *(bf16x8*)(dstp + 8) = v1;
  }
}

// ---- generic MFMA GEMM.
// MERGE=1: A[gm][k] = (sum_q Opart[q][k/32][gm][k%32]) / (sum_q Lpart[q][k/32][gm])
// ATOM=1: atomicAdd partial into Cf (bias added by z==0 block); else bf16 out + ACT.
template<int ACT, int ATOM, int MERGE>
__global__ __launch_bounds__(256) void mgemm(const short* __restrict__ A,
    const float* __restrict__ Op, const float* __restrict__ Lp,
    const short* __restrict__ W, const float* __restrict__ bs,
    float* __restrict__ Cf, short* __restrict__ Cb,
    int M, int Nn, int Kc, int Kstride){
  __shared__ __align__(16) short As[64][40], Ws[64][40];
  const int tid = threadIdx.x, lane = tid & 63, wave = tid >> 6;
  const int col = lane & 15, quad = lane >> 4;
  const int wm = wave & 1, wn = wave >> 1;
  const int bm = blockIdx.x * 64, bn = blockIdx.y * 64;
  const int koff = blockIdx.z * Kc;
  const f32x4 zero4 = {0.f, 0.f, 0.f, 0.f};
  f32x4 acc[2][2] = {{zero4, zero4}, {zero4, zero4}};
  const int row = tid >> 2, seg = tid & 3;
  for (int k0 = 0; k0 < Kc; k0 += 32){
    __syncthreads();
    int gm = bm + row;
    if (MERGE){
      int kg = koff + k0 + seg * 8;
      int hh = kg >> 5, d0 = kg & 31;
      short sarr[8] = {0,0,0,0,0,0,0,0};
      if (gm < M){
        float o0=0,o1=0,o2=0,o3=0,o4=0,o5=0,o6=0,o7=0, sl=0.f;
        #pragma unroll
        for (int q = 0; q < NSPLIT; q++){
          long rb = (long)(q * H_ + hh) * RPAD + gm;
          const float* op = Op + rb * HD_ + d0;
          float4 v0 = *(const float4*)op, v1 = *(const float4*)(op + 4);
          o0 += v0.x; o1 += v0.y; o2 += v0.z; o3 += v0.w;
          o4 += v1.x; o5 += v1.y; o6 += v1.z; o7 += v1.w;
          sl += Lp[rb];
        }
        float inv = 1.0f / sl;
        sarr[0]=(short)f2b(o0*inv); sarr[1]=(short)f2b(o1*inv);
        sarr[2]=(short)f2b(o2*inv); sarr[3]=(short)f2b(o3*inv);
        sarr[4]=(short)f2b(o4*inv); sarr[5]=(short)f2b(o5*inv);
        sarr[6]=(short)f2b(o6*inv); sarr[7]=(short)f2b(o7*inv);
      }
      *(bf16x8*)&As[row][seg * 8] = *(bf16x8*)sarr;
    } else {
      bf16x8 av = (bf16x8)(short)0;
      if (gm < M) av = *(const bf16x8*)(A + (long)gm * Kstride + koff + k0 + seg * 8);
      *(bf16x8*)&As[row][seg * 8] = av;
    }
    *(bf16x8*)&Ws[row][seg * 8] =
      *(const bf16x8*)(W + (long)(bn + row) * Kstride + koff + k0 + seg * 8);
    __syncthreads();
    bf16x8 a0 = *(const bf16x8*)&As[wm * 32 + col][quad * 8];
    bf16x8 a1 = *(const bf16x8*)&As[wm * 32 + 16 + col][quad * 8];
    bf16x8 b0 = *(const bf16x8*)&Ws[wn * 32 + col][quad * 8];
    bf16x8 b1 = *(const bf16x8*)&Ws[wn * 32 + 16 + col][quad * 8];
    acc[0][0] = __builtin_amdgcn_mfma_f32_16x16x32_bf16(a0, b0, acc[0][0], 0, 0, 0);
    acc[0][1] = __builtin_amdgcn_mfma_f32_16x16x32_bf16(a0, b1, acc[0][1], 0, 0, 0);
    acc[1][0] = __builtin_amdgcn_mfma_f32_16x16x32_bf16(a1, b0, acc[1][0], 0, 0, 0);
    acc[1][1] = __builtin_amdgcn_mfma_f32_16x16x32_bf16(a1, b1, acc[1][1], 0, 0, 0);
  }
  #pragma unroll
  for (int i = 0; i < 2; i++)
    #pragma unroll
    for (int j = 0; j < 2; j++)
      #pragma unroll
      for (int r = 0; r < 4; r++){
        int gm = bm + wm * 32 + i * 16 + quad * 4 + r;
        if (gm >= M) continue;
        int gn = bn + wn * 32 + j * 16 + col;
        if (ATOM){
          float v = acc[i][j][r] + (blockIdx.z == 0 ? bs[gn] : 0.f);
          atomicAdd(&Cf[(long)gm * Nn + gn], v);
        } else {
          float v = acc[i][j][r] + bs[gn];
          if (ACT == 1) v = v * 0.5f * (1.0f + erff(v * 0.70710678118654752f));
          Cb[(long)gm * Nn + gn] = (short)f2b(v);
        }
      }
}

// ---- flash attention, fixed-shift softmax in exp2 domain.
// grid (33, H, NSPLIT); block = 4 waves x 16 rows.
// Key permutation: MFMA sub-tile t4 covers key j0 + col*4 + t4, so each lane's
// 4 bias bytes per row are ONE coalesced global dword, and P is written with
// packed ds_write_b64. K/V staged in LDS (r12 showed direct-global feeding
// regresses: L2 latency lands in the serial per-wave chain).
__global__ __launch_bounds__(256) void fattn_k(const short* __restrict__ Qb,
    const short* __restrict__ Kb, const short* __restrict__ Vtg,
    const unsigned char* __restrict__ bias8, float* __restrict__ Opart,
    float* __restrict__ Lpart){
  __shared__ __align__(16) short Ks[64][42];   // stride 42: 2-way max on permuted reads
  __shared__ __align__(16) short Vt[32][72];
  __shared__ __align__(16) short Ps[4][16][72];

  const int tid = threadIdx.x, wave = tid >> 6, lane = tid & 63;
  const int col = lane & 15, quad = lane >> 4;
  const int h = blockIdx.y, qz = blockIdx.z;
  const int i0 = blockIdx.x * 64 + wave * 16;
  const int t0 = (qz == 0) ? 0 : 9 + 8 * (qz - 1);   // 0,9,17,25
  const int t1 = t0 + ((qz == 0) ? 9 : 8);           // 33 tiles total

  int qrow = min(i0 + col, NF - 1);
  bf16x8 qf = *(const bf16x8*)(Qb + (long)qrow * D_ + h * HD_ + quad * 8);

  int brow[4];
  #pragma unroll
  for (int r = 0; r < 4; r++) brow[r] = min(i0 + quad * 4 + r, NF - 1);

  f32x4 oacc0 = {0.f, 0.f, 0.f, 0.f}, oacc1 = {0.f, 0.f, 0.f, 0.f};
  float rs[4] = {0.f, 0.f, 0.f, 0.f};
  const f32x4 zero4 = {0.f, 0.f, 0.f, 0.f};
  short* Pp = &Ps[wave][0][0];

  for (int t = t0; t < t1; t++){
    const int j0 = t * 64;
    // bias: one dword per row (4 fp8 bytes for t4=0..3), coalesced across col
    unsigned bw[4];
    #pragma unroll
    for (int r = 0; r < 4; r++)
      bw[r] = *(const unsigned*)(bias8 + (long)(h * NF + brow[r]) * BSTRIDE + j0 + col * 4);
    __syncthreads();
    { // K tile: 64 keys x 32 dims
      int key = tid >> 2, seg = tid & 3;
      int j = j0 + key;
      bf16x8 kv = (bf16x8)(short)0;
      if (j < NF) kv = *(const bf16x8*)(Kb + (long)j * D_ + h * HD_ + seg * 8);
      *(bf16x8*)&Ks[key][seg * 8] = kv;
    }
    { // V tile (pre-transposed): 32 dims x 64 keys
      int d = tid >> 3, seg = tid & 7;
      *(bf16x8*)&Vt[d][seg * 8] =
        *(const bf16x8*)(Vtg + (long)(h * HD_ + d) * BSTRIDE + j0 + seg * 8);
    }
    __syncthreads();

    f32x4 sacc[4];
    #pragma unroll
    for (int t4 = 0; t4 < 4; t4++){
      bf16x8 kf = *(const bf16x8*)&Ks[col * 4 + t4][quad * 8];
      sacc[t4] = __builtin_amdgcn_mfma_f32_16x16x32_bf16(qf, kf, zero4, 0, 0, 0);
    }

    const bool tail = (j0 + 64 > NF);
    #pragma unroll
    for (int r = 0; r < 4; r++){
      // fp8 byte-select must be a literal: decode all 4 bytes explicitly
      float bv0 = __builtin_amdgcn_cvt_f32_fp8((int)bw[r], 0);
      float bv1 = __builtin_amdgcn_cvt_f32_fp8((int)bw[r], 1);
      float bv2 = __builtin_amdgcn_cvt_f32_fp8((int)bw[r], 2);
      float bv3 = __builtin_amdgcn_cvt_f32_fp8((int)bw[r], 3);
      float bvv[4] = {bv0, bv1, bv2, bv3};
      unsigned short pb[4];
      #pragma unroll
      for (int t4 = 0; t4 < 4; t4++){
        float p = exp2f(sacc[t4][r] + bvv[t4]);   // Q pre-scaled by scale*log2e
        if (tail && (j0 + col * 4 + t4 >= NF)) p = 0.f;
        unsigned pu = __float_as_uint(p) & 0xffff0000u;  // RTZ to bf16
        rs[r] += __uint_as_float(pu);                    // consistent with PV
        pb[t4] = (unsigned short)(pu >> 16);
      }
      unsigned u0 = (unsigned)pb[0] | ((unsigned)pb[1] << 16);
      unsigned u1 = (unsigned)pb[2] | ((unsigned)pb[3] << 16);
      *(uint2*)&Pp[(quad * 4 + r) * 72 + col * 4] = make_uint2(u0, u1);
    }

    #pragma unroll
    for (int ks = 0; ks < 2; ks++){
      bf16x8 af = *(const bf16x8*)&Pp[col * 72 + ks * 32 + quad * 8];
      bf16x8 v0 = *(const bf16x8*)&Vt[col][ks * 32 + quad * 8];
      bf16x8 v1 = *(const bf16x8*)&Vt[16 + col][ks * 32 + quad * 8];
      oacc0 = __builtin_amdgcn_mfma_f32_16x16x32_bf16(af, v0, oacc0, 0, 0, 0);
      oacc1 = __builtin_amdgcn_mfma_f32_16x16x32_bf16(af, v1, oacc1, 0, 0, 0);
    }
  }

  #pragma unroll
  for (int r = 0; r < 4; r++){
    #pragma unroll
    for (int o = 1; o < 16; o <<= 1) rs[r] += __shfl_xor(rs[r], o, 64);
  }
  long pi = ((long)qz * H_ + h) * RPAD + i0 + quad * 4;
  #pragma unroll
  for (int r = 0; r < 4; r++){
    Opart[(pi + r) * HD_ + col] = oacc0[r];
    Opart[(pi + r) * HD_ + 16 + col] = oacc1[r];
    if (col == 0) Lpart[pi + r] = rs[r];
  }
}

extern "C" void kernel_launch(void* const* d_in, const int* in_sizes, int n_in,
                              void* d_out, int out_size, void* d_ws, size_t ws_size,
                              hipStream_t stream){
  const float* x    = (const float*)d_in[0];
  const float* ea   = (const float*)d_in[1];
  const float* npw  = (const float*)d_in[2];
  const float* npb  = (const float*)d_in[3];
  const float* inE  = (const float*)d_in[4];
  const float* outE = (const float*)d_in[5];
  const float* db   = (const float*)d_in[6];
  const float* epw  = (const float*)d_in[7];
  const float* epb  = (const float*)d_in[8];
  const float* cls  = (const float*)d_in[9];
  const float* qw   = (const float*)d_in[10];
  const float* qb   = (const float*)d_in[11];
  const float* kw   = (const float*)d_in[12];
  const float* kb   = (const float*)d_in[13];
  const float* vw   = (const float*)d_in[14];
  const float* vb   = (const float*)d_in[15];
  const float* ow   = (const float*)d_in[16];
  const float* ob   = (const float*)d_in[17];
  const float* f1w  = (const float*)d_in[18];
  const float* f1b  = (const float*)d_in[19];
  const float* f2w  = (const float*)d_in[20];
  const float* f2bp = (const float*)d_in[21];
  const float* ln1s = (const float*)d_in[22];
  const float* ln1b = (const float*)d_in[23];
  const float* ln2s = (const float*)d_in[24];
  const float* ln2b = (const float*)d_in[25];
  const float* fns  = (const float*)d_in[26];
  const float* fnb  = (const float*)d_in[27];
  const int*   ei   = (const int*)d_in[28];
  const int*   dist = (const int*)d_in[29];

  float* ws = (float*)d_ws;
  long off = 0;
  float* h     = ws + off; off += (long)NF * D_;
  float* Opart = ws + off; off += (long)NSPLIT * H_ * RPAD * HD_;
  float* Lpart = ws + off; off += (long)NSPLIT * H_ * RPAD;
  unsigned char* bias8 = (unsigned char*)(ws + off);
  off += ((long)H_ * NF * BSTRIDE + 3) / 4;
  short* hnb   = (short*)(ws + off); off += ((long)NF * D_ + 1) / 2;
  short* QKb   = (short*)(ws + off); off += (long)NF * D_;      // Q then K
  short* Vtg   = (short*)(ws + off); off += ((long)D_ * BSTRIDE + 1) / 2;
  short* midb  = (short*)(ws + off); off += ((long)NF * FFN_ + 1) / 2;
  short* wqkv  = (short*)(ws + off); off += ((long)3 * L_ * D_ * D_ + 1) / 2;
  short* owb   = (short*)(ws + off); off += ((long)L_ * D_ * D_ + 1) / 2;
  short* f1wb  = (short*)(ws + off); off += ((long)L_ * FFN_ * D_ + 1) / 2;
  short* f2wb  = (short*)(ws + off); off += ((long)L_ * FFN_ * D_ + 1) / 2;
  int*   ind   = (int*)(ws + off);
  int*   outd  = ind + N_;

  zero_int<<<(2 * N_ + 255) / 256, 256, 0, stream>>>(ind, 2 * N_);
  deg_count<<<(E_ + 255) / 256, 256, 0, stream>>>(ei, ind, outd);
  embed_k<<<NF, D_, 0, stream>>>(x, npw, npb, inE, outE, ind, outd, cls, h);
  bias_fill<<<NF, 256, 0, stream>>>(dist, db, bias8);
  edge_bias<<<(E_ + 255) / 256, 256, 0, stream>>>(ea, epw, epb, ei, bias8);
  {
    long LFD = (long)L_ * FFN_ * D_;
    w2b_all<<<(int)((LFD + 255) / 256), 256, 0, stream>>>(qw, kw, vw, ow, f1w, f2w,
                                                          wqkv, owb, f1wb, f2wb);
  }

  dim3 gQKV((NF + 63) / 64, D_ / 64, 3);
  dim3 gO((NF + 63) / 64, D_ / 64, 2);
  dim3 gF((NF + 63) / 64, FFN_ / 64, 1);
  dim3 gF2((NF + 63) / 64, D_ / 64, 4);
  dim3 gA((NF + 63) / 64, H_, NSPLIT);
  for (int l = 0; l < L_; l++){
    ln_k<<<NF, D_, 0, stream>>>(h, ln1s + l * D_, ln1b + l * D_, nullptr, hnb, 0);
    qkv_gemm<<<gQKV, 256, 0, stream>>>(hnb, wqkv, qb + l * D_, kb + l * D_, vb + l * D_,
                                       QKb, Vtg, l);
    fattn_k<<<gA, 256, 0, stream>>>(QKb, QKb + (long)NF * D_, Vtg, bias8, Opart, Lpart);
    mgemm<0,1,1><<<gO, 256, 0, stream>>>(nullptr, Opart, Lpart,
                                         owb + (long)l * D_ * D_, ob + l * D_,
                                         h, nullptr, NF, D_, 128, D_);
    ln_k<<<NF, D_, 0, stream>>>(h, ln2s + l * D_, ln2b + l * D_, nullptr, hnb, 0);
    mgemm<1,0,0><<<gF, 256, 0, stream>>>(hnb, nullptr, nullptr,
                                         f1wb + (long)l * FFN_ * D_, f1b + l * FFN_,
                                         nullptr, midb, NF, FFN_, D_, D_);
    mgemm<0,1,0><<<gF2, 256, 0, stream>>>(midb, nullptr, nullptr,
                                          f2wb + (long)l * FFN_ * D_, f2bp + l * D_,
                                          h, nullptr, NF, D_, 256, FFN_);
  }
  ln_k<<<NF, D_, 0, stream>>>(h, fns, fnb, (float*)d_out, nullptr, 1);
}